// Round 1
// baseline (336.947 us; speedup 1.0000x reference)
//
#include <hip/hip_runtime.h>

#define NBINS 10
#define INV 0.1f   // == float(1.0/10), matches reference's inv in f32

__global__ __launch_bounds__(256) void trust_kernel(
    const int2*  __restrict__ perf,       // [T,N] packed (fail,success)
    const float* __restrict__ obs_sens,   // [T,N]
    const float* __restrict__ obs_proc,   // [T,N]
    const float* __restrict__ pred_sens,  // [N]
    const float* __restrict__ pred_proc,  // [N]
    const float* __restrict__ betas,      // [2]
    const float* __restrict__ zetas,      // [2]
    float*       __restrict__ out,        // [N]
    int N, int T)
{
    int n = blockIdx.x * blockDim.x + threadIdx.x;
    if (n >= N) return;

    float lo0 = 0.0f, hi0 = 1.0f;   // channel 0: sens
    float lo1 = 0.0f, hi1 = 1.0f;   // channel 1: proc

    #pragma unroll 4
    for (int t = 0; t < T; ++t) {
        size_t idx = (size_t)t * (size_t)N + (size_t)n;
        int2  pv = perf[idx];
        float c0 = obs_sens[idx];
        float c1 = obs_proc[idx];
        bool s0 = (pv.x != 0);           // fail bit
        bool s1 = (pv.y != 0);           // success bit
        bool succ = (!s0) && s1;
        bool fail = s0 && (!s1);

        // ---- channel 0 ----
        {
            float lo = lo0, hi = hi0, cap = c0;
            if (succ) {
                if (cap > hi)      hi = cap;
                else if (cap > lo) lo = cap;
            } else if (fail) {
                if (cap < lo)      lo = cap;
                else if (cap < hi) hi = cap;
            }
            if (lo == hi) {                 // degenerate-interval fixup
                if (hi == 0.0f) hi = INV;
                else            lo = hi - INV;
            }
            lo0 = lo; hi0 = hi;
        }
        // ---- channel 1 ----
        {
            float lo = lo1, hi = hi1, cap = c1;
            if (succ) {
                if (cap > hi)      hi = cap;
                else if (cap > lo) lo = cap;
            } else if (fail) {
                if (cap < lo)      lo = cap;
                else if (cap < hi) hi = cap;
            }
            if (lo == hi) {
                if (hi == 0.0f) hi = INV;
                else            lo = hi - INV;
            }
            lo1 = lo; hi1 = hi;
        }
    }

    // ---- epilogue: trust = prod_ch ( sum_k d_ch[k]*m_ch[k] / sum_k m_ch[k] ) ----
    float beta0 = betas[0], beta1 = betas[1];
    float z0 = zetas[0],    z1 = zetas[1];
    float e0 = -(z0 * z0),  e1 = -(z1 * z1);
    float r0 = pred_sens[n], r1 = pred_proc[n];

    float sm0 = 0.0f, sd0 = 0.0f, sm1 = 0.0f, sd1 = 0.0f;
    #pragma unroll
    for (int k = 0; k < NBINS; ++k) {
        float s = ((float)k + 0.5f) * INV;   // exact same arithmetic as reference steps
        if (s >= lo0 && s <= hi0) {
            float p = beta0 * (r0 - s);
            sd0 += powf(1.0f + expf(p), e0);
            sm0 += 1.0f;
        }
        if (s >= lo1 && s <= hi1) {
            float p = beta1 * (r1 - s);
            sd1 += powf(1.0f + expf(p), e1);
            sm1 += 1.0f;
        }
    }

    out[n] = (sd0 / sm0) * (sd1 / sm1);
}

extern "C" void kernel_launch(void* const* d_in, const int* in_sizes, int n_in,
                              void* d_out, int out_size, void* d_ws, size_t ws_size,
                              hipStream_t stream) {
    // setup_inputs order:
    // 0 inptasksobs (unused)  1 inptasksperf [T,N,2] int32  2 inptaskspred (unused)
    // 3 num_obs_tasks [N]     4 tasksobsids (unused)        5 taskspredids (unused)
    // 6 obs_task_sens_cap_seq [T,N]  7 pred_task_sens_cap [N,1]
    // 8 obs_task_proc_cap_seq [T,N]  9 pred_task_proc_cap [N,1]
    // 10 betas [2]            11 zetas [2]
    const int*   perf      = (const int*)d_in[1];
    const float* obs_sens  = (const float*)d_in[6];
    const float* pred_sens = (const float*)d_in[7];
    const float* obs_proc  = (const float*)d_in[8];
    const float* pred_proc = (const float*)d_in[9];
    const float* betas     = (const float*)d_in[10];
    const float* zetas     = (const float*)d_in[11];

    int N = in_sizes[3];            // num_obs_tasks has N elements
    int T = in_sizes[6] / N;        // obs_task_sens_cap_seq is [T,N]

    int block = 256;
    int grid  = (N + block - 1) / block;
    trust_kernel<<<grid, block, 0, stream>>>(
        (const int2*)perf, obs_sens, obs_proc, pred_sens, pred_proc,
        betas, zetas, (float*)d_out, N, T);
}

// Round 3
// 301.734 us; speedup vs baseline: 1.1167x; 1.1167x over previous
//
#include <hip/hip_runtime.h>

#define NBINS 10
#define INV 0.1f   // == float(1.0/10), matches reference's inv in f32
#define UNROLL 8

__device__ __forceinline__ void update_state(float& lo, float& hi, float cap,
                                             bool succ, bool fail) {
    // success branch: if cap > hi: hi = cap; elif cap > lo: lo = cap
    float s_hi = (cap > hi) ? cap : hi;
    float s_lo = ((cap <= hi) && (cap > lo)) ? cap : lo;
    // failure branch: if cap < lo: lo = cap; elif cap < hi: hi = cap
    float f_lo = (cap < lo) ? cap : lo;
    float f_hi = ((cap >= lo) && (cap < hi)) ? cap : hi;
    float lo2 = succ ? s_lo : (fail ? f_lo : lo);
    float hi2 = succ ? s_hi : (fail ? f_hi : hi);
    // degenerate-interval fixup
    bool eq = (lo2 == hi2);
    hi = (eq && (hi2 == 0.0f)) ? INV : hi2;
    lo = (eq && (hi2 != 0.0f)) ? (hi2 - INV) : lo2;
}

__global__ __launch_bounds__(256) void trust_kernel(
    const long long* __restrict__ perf,   // [T,N] packed (fail,success) as i64
    const float* __restrict__ obs_sens,   // [T,N]
    const float* __restrict__ obs_proc,   // [T,N]
    const float* __restrict__ pred_sens,  // [N]
    const float* __restrict__ pred_proc,  // [N]
    const float* __restrict__ betas,      // [2]
    const float* __restrict__ zetas,      // [2]
    float*       __restrict__ out,        // [N]
    int N, int T)
{
    int n = blockIdx.x * blockDim.x + threadIdx.x;
    if (n >= N) return;

    float lo0 = 0.0f, hi0 = 1.0f;   // channel 0: sens
    float lo1 = 0.0f, hi1 = 1.0f;   // channel 1: proc

    int t = 0;
    for (; t + UNROLL <= T; t += UNROLL) {
        long long pv[UNROLL];
        float c0[UNROLL], c1[UNROLL];
        // Stage ALL loads first so up to 3*UNROLL vector loads are in flight
        // per wave before any consumer forces a waitcnt.
        #pragma unroll
        for (int u = 0; u < UNROLL; ++u) {
            size_t idx = (size_t)(t + u) * (size_t)N + (size_t)n;
            pv[u] = __builtin_nontemporal_load(&perf[idx]);
            c0[u] = __builtin_nontemporal_load(&obs_sens[idx]);
            c1[u] = __builtin_nontemporal_load(&obs_proc[idx]);
        }
        #pragma unroll
        for (int u = 0; u < UNROLL; ++u) {
            bool s0 = ((int)(pv[u] & 0xffffffffLL) != 0);        // fail bit (low word)
            bool s1 = ((int)((unsigned long long)pv[u] >> 32) != 0); // success bit (high word)
            bool succ = (!s0) && s1;
            bool fail = s0 && (!s1);
            update_state(lo0, hi0, c0[u], succ, fail);
            update_state(lo1, hi1, c1[u], succ, fail);
        }
    }
    for (; t < T; ++t) {   // tail (T not multiple of UNROLL)
        size_t idx = (size_t)t * (size_t)N + (size_t)n;
        long long pv = perf[idx];
        float c0 = obs_sens[idx];
        float c1 = obs_proc[idx];
        bool s0 = ((int)(pv & 0xffffffffLL) != 0);
        bool s1 = ((int)((unsigned long long)pv >> 32) != 0);
        bool succ = (!s0) && s1;
        bool fail = s0 && (!s1);
        update_state(lo0, hi0, c0, succ, fail);
        update_state(lo1, hi1, c1, succ, fail);
    }

    // ---- epilogue: trust = prod_ch ( sum_k d_ch[k]*m_ch[k] / sum_k m_ch[k] ) ----
    float beta0 = betas[0], beta1 = betas[1];
    float z0 = zetas[0],    z1 = zetas[1];
    float e0 = -(z0 * z0),  e1 = -(z1 * z1);
    float r0 = pred_sens[n], r1 = pred_proc[n];

    float sm0 = 0.0f, sd0 = 0.0f, sm1 = 0.0f, sd1 = 0.0f;
    #pragma unroll
    for (int k = 0; k < NBINS; ++k) {
        float s = ((float)k + 0.5f) * INV;   // same arithmetic as reference steps
        if (s >= lo0 && s <= hi0) {
            float p = beta0 * (r0 - s);
            sd0 += powf(1.0f + expf(p), e0);
            sm0 += 1.0f;
        }
        if (s >= lo1 && s <= hi1) {
            float p = beta1 * (r1 - s);
            sd1 += powf(1.0f + expf(p), e1);
            sm1 += 1.0f;
        }
    }

    out[n] = (sd0 / sm0) * (sd1 / sm1);
}

extern "C" void kernel_launch(void* const* d_in, const int* in_sizes, int n_in,
                              void* d_out, int out_size, void* d_ws, size_t ws_size,
                              hipStream_t stream) {
    // setup_inputs order:
    // 0 inptasksobs (unused)  1 inptasksperf [T,N,2] int32  2 inptaskspred (unused)
    // 3 num_obs_tasks [N]     4 tasksobsids (unused)        5 taskspredids (unused)
    // 6 obs_task_sens_cap_seq [T,N]  7 pred_task_sens_cap [N,1]
    // 8 obs_task_proc_cap_seq [T,N]  9 pred_task_proc_cap [N,1]
    // 10 betas [2]            11 zetas [2]
    const long long* perf   = (const long long*)d_in[1];
    const float* obs_sens   = (const float*)d_in[6];
    const float* pred_sens  = (const float*)d_in[7];
    const float* obs_proc   = (const float*)d_in[8];
    const float* pred_proc  = (const float*)d_in[9];
    const float* betas      = (const float*)d_in[10];
    const float* zetas      = (const float*)d_in[11];

    int N = in_sizes[3];            // num_obs_tasks has N elements
    int T = in_sizes[6] / N;        // obs_task_sens_cap_seq is [T,N]

    int block = 256;
    int grid  = (N + block - 1) / block;
    trust_kernel<<<grid, block, 0, stream>>>(
        perf, obs_sens, obs_proc, pred_sens, pred_proc,
        betas, zetas, (float*)d_out, N, T);
}

// Round 4
// 301.090 us; speedup vs baseline: 1.1191x; 1.0021x over previous
//
#include <hip/hip_runtime.h>

#define NBINS 10
#define INV 0.1f   // == float(1.0/10), matches reference's inv in f32
#define UNROLL 32  // deep staging: occupancy is grid-limited (1 wave/SIMD),
                   // so VGPRs are free — 32*(2+1+1)=128 data VGPRs, 96 loads
                   // in flight saturates the outstanding-load window.

__device__ __forceinline__ void update_state(float& lo, float& hi, float cap,
                                             bool succ, bool fail) {
    // success branch: if cap > hi: hi = cap; elif cap > lo: lo = cap
    float s_hi = (cap > hi) ? cap : hi;
    float s_lo = ((cap <= hi) && (cap > lo)) ? cap : lo;
    // failure branch: if cap < lo: lo = cap; elif cap < hi: hi = cap
    float f_lo = (cap < lo) ? cap : lo;
    float f_hi = ((cap >= lo) && (cap < hi)) ? cap : hi;
    float lo2 = succ ? s_lo : (fail ? f_lo : lo);
    float hi2 = succ ? s_hi : (fail ? f_hi : hi);
    // degenerate-interval fixup
    bool eq = (lo2 == hi2);
    hi = (eq && (hi2 == 0.0f)) ? INV : hi2;
    lo = (eq && (hi2 != 0.0f)) ? (hi2 - INV) : lo2;
}

__global__ __launch_bounds__(256, 1) void trust_kernel(
    const long long* __restrict__ perf,   // [T,N] packed (fail,success) as i64
    const float* __restrict__ obs_sens,   // [T,N]
    const float* __restrict__ obs_proc,   // [T,N]
    const float* __restrict__ pred_sens,  // [N]
    const float* __restrict__ pred_proc,  // [N]
    const float* __restrict__ betas,      // [2]
    const float* __restrict__ zetas,      // [2]
    float*       __restrict__ out,        // [N]
    int N, int T)
{
    int n = blockIdx.x * blockDim.x + threadIdx.x;
    if (n >= N) return;

    float lo0 = 0.0f, hi0 = 1.0f;   // channel 0: sens
    float lo1 = 0.0f, hi1 = 1.0f;   // channel 1: proc

    int t = 0;
    for (; t + UNROLL <= T; t += UNROLL) {
        long long pv[UNROLL];
        float c0[UNROLL], c1[UNROLL];
        // Stage ALL loads first: 3*UNROLL independent vector loads in flight
        // before any consumer forces a waitcnt. Only T/UNROLL=2 latency
        // drains total per thread.
        #pragma unroll
        for (int u = 0; u < UNROLL; ++u) {
            size_t idx = (size_t)(t + u) * (size_t)N + (size_t)n;
            pv[u] = __builtin_nontemporal_load(&perf[idx]);
            c0[u] = __builtin_nontemporal_load(&obs_sens[idx]);
            c1[u] = __builtin_nontemporal_load(&obs_proc[idx]);
        }
        #pragma unroll
        for (int u = 0; u < UNROLL; ++u) {
            bool s0 = ((int)(pv[u] & 0xffffffffLL) != 0);            // fail bit (low word)
            bool s1 = ((int)((unsigned long long)pv[u] >> 32) != 0); // success bit (high word)
            bool succ = (!s0) && s1;
            bool fail = s0 && (!s1);
            update_state(lo0, hi0, c0[u], succ, fail);
            update_state(lo1, hi1, c1[u], succ, fail);
        }
    }
    for (; t < T; ++t) {   // tail (T not multiple of UNROLL)
        size_t idx = (size_t)t * (size_t)N + (size_t)n;
        long long pv = perf[idx];
        float c0 = obs_sens[idx];
        float c1 = obs_proc[idx];
        bool s0 = ((int)(pv & 0xffffffffLL) != 0);
        bool s1 = ((int)((unsigned long long)pv >> 32) != 0);
        bool succ = (!s0) && s1;
        bool fail = s0 && (!s1);
        update_state(lo0, hi0, c0, succ, fail);
        update_state(lo1, hi1, c1, succ, fail);
    }

    // ---- epilogue: trust = prod_ch ( sum_k d_ch[k]*m_ch[k] / sum_k m_ch[k] ) ----
    float beta0 = betas[0], beta1 = betas[1];
    float z0 = zetas[0],    z1 = zetas[1];
    float e0 = -(z0 * z0),  e1 = -(z1 * z1);
    float r0 = pred_sens[n], r1 = pred_proc[n];

    float sm0 = 0.0f, sd0 = 0.0f, sm1 = 0.0f, sd1 = 0.0f;
    #pragma unroll
    for (int k = 0; k < NBINS; ++k) {
        float s = ((float)k + 0.5f) * INV;   // same arithmetic as reference steps
        if (s >= lo0 && s <= hi0) {
            float p = beta0 * (r0 - s);
            sd0 += powf(1.0f + expf(p), e0);
            sm0 += 1.0f;
        }
        if (s >= lo1 && s <= hi1) {
            float p = beta1 * (r1 - s);
            sd1 += powf(1.0f + expf(p), e1);
            sm1 += 1.0f;
        }
    }

    out[n] = (sd0 / sm0) * (sd1 / sm1);
}

extern "C" void kernel_launch(void* const* d_in, const int* in_sizes, int n_in,
                              void* d_out, int out_size, void* d_ws, size_t ws_size,
                              hipStream_t stream) {
    // setup_inputs order:
    // 0 inptasksobs (unused)  1 inptasksperf [T,N,2] int32  2 inptaskspred (unused)
    // 3 num_obs_tasks [N]     4 tasksobsids (unused)        5 taskspredids (unused)
    // 6 obs_task_sens_cap_seq [T,N]  7 pred_task_sens_cap [N,1]
    // 8 obs_task_proc_cap_seq [T,N]  9 pred_task_proc_cap [N,1]
    // 10 betas [2]            11 zetas [2]
    const long long* perf   = (const long long*)d_in[1];
    const float* obs_sens   = (const float*)d_in[6];
    const float* pred_sens  = (const float*)d_in[7];
    const float* obs_proc   = (const float*)d_in[8];
    const float* pred_proc  = (const float*)d_in[9];
    const float* betas      = (const float*)d_in[10];
    const float* zetas      = (const float*)d_in[11];

    int N = in_sizes[3];            // num_obs_tasks has N elements
    int T = in_sizes[6] / N;        // obs_task_sens_cap_seq is [T,N]

    int block = 256;
    int grid  = (N + block - 1) / block;
    trust_kernel<<<grid, block, 0, stream>>>(
        perf, obs_sens, obs_proc, pred_sens, pred_proc,
        betas, zetas, (float*)d_out, N, T);
}